// Round 9
// baseline (2203.619 us; speedup 1.0000x reference)
//
#include <hip/hip_runtime.h>
#include <stdint.h>

#define SEQ    512
#define NBATCH 64
#define HID    1024
#define GDIM   4096

typedef __attribute__((ext_vector_type(4))) float          f32x4;
typedef __attribute__((ext_vector_type(8))) short          s16x8;
typedef __attribute__((ext_vector_type(4))) unsigned short u16x4;
typedef __attribute__((ext_vector_type(4))) unsigned int   u32x4;

#define MFMA_BF16(a,b,c) __builtin_amdgcn_mfma_f32_16x16x32_bf16((a),(b),(c),0,0,0)

__device__ __forceinline__ unsigned short f2bf(float f){
  union { float f; unsigned u; } v; v.f = f;
  unsigned r = v.u + 0x7fffu + ((v.u >> 16) & 1u);
  return (unsigned short)(r >> 16);
}

__device__ __forceinline__ void gload_lds16(const void* g, void* l){
  __builtin_amdgcn_global_load_lds((const __attribute__((address_space(1))) void*)g,
                                   (__attribute__((address_space(3))) void*)l,
                                   16, 0, 0);
}

// ---------------- fp32 -> bf16 bulk convert (n4 = elements/4) ----------------
__global__ __launch_bounds__(256) void cvt_bf16(const float* __restrict__ s,
                                                unsigned short* __restrict__ d, int n4){
  int i = blockIdx.x*256 + threadIdx.x;
  if (i >= n4) return;
  f32x4 v = *(const f32x4*)(s + (size_t)i*4);
  u16x4 o;
  o[0]=f2bf(v[0]); o[1]=f2bf(v[1]); o[2]=f2bf(v[2]); o[3]=f2bf(v[3]);
  *(u16x4*)(d + (size_t)i*4) = o;
}

// ---------------- init: h0 -> hring slot 0 (bf16, LINEAR), c0 -> cstate ----
__global__ __launch_bounds__(256) void init_state(const float* __restrict__ h0,
                                                  const float* __restrict__ c0,
                                                  unsigned short* __restrict__ hring,
                                                  float* __restrict__ cstate){
  int i = blockIdx.x*256 + threadIdx.x;   // 65536 total
  hring[i]  = f2bf(h0[i]);
  cstate[i] = c0[i];
}

// ---------------- x_proj GEMM: C[M][4096] = A[M][1024] * Bw[4096][1024]^T + bias ----
__global__ __launch_bounds__(256,1) void gemm_xproj(
    const unsigned short* __restrict__ A,   // bf16 [M][1024]
    const unsigned short* __restrict__ Bw,  // bf16 [4096][1024]
    const float* __restrict__ bih, const float* __restrict__ bhh,
    float* __restrict__ C, int M)
{
  __shared__ unsigned short Al[2][128*64];
  __shared__ unsigned short Bl[2][128*64];

  const int bm = blockIdx.x >> 5;
  const int bn = blockIdx.x & 31;
  const int tid = threadIdx.x;
  const int wv = tid >> 6, l = tid & 63;
  const int wm = wv >> 1, wn = wv & 1;
  const int c16 = l & 15, rq = l >> 4;

  const unsigned short* Ab = A  + (size_t)bm*128*1024;
  const unsigned short* Bb = Bw + (size_t)bn*128*1024;

  f32x4 acc[4][4];
#pragma unroll
  for (int i=0;i<4;++i)
#pragma unroll
    for (int j=0;j<4;++j) acc[i][j] = (f32x4){0.f,0.f,0.f,0.f};

  auto stage = [&](int buf, int kt){
    const int k0 = kt*64;
    const int rsub = wv*8 + (l>>3);
    const int col  = (l&7)*8;
#pragma unroll
    for (int is=0; is<4; ++is){
      const int row = is*32 + rsub;
      gload_lds16(Ab + (size_t)row*1024 + k0 + col, &Al[buf][row*64 + col]);
      gload_lds16(Bb + (size_t)row*1024 + k0 + col, &Bl[buf][row*64 + col]);
    }
  };

  stage(0, 0);
  asm volatile("s_waitcnt vmcnt(0)" ::: "memory");
  __syncthreads();

  for (int kt = 0; kt < 16; ++kt){
    const int cur = kt & 1;
    if (kt < 15) stage(cur^1, kt+1);
#pragma unroll
    for (int ks=0; ks<2; ++ks){
      s16x8 afr[4], bfr[4];
#pragma unroll
      for (int mi=0;mi<4;++mi)
        afr[mi] = *(const s16x8*)&Al[cur][(wm*64 + mi*16 + c16)*64 + ks*32 + rq*8];
#pragma unroll
      for (int ni=0;ni<4;++ni)
        bfr[ni] = *(const s16x8*)&Bl[cur][(wn*64 + ni*16 + c16)*64 + ks*32 + rq*8];
#pragma unroll
      for (int mi=0;mi<4;++mi)
#pragma unroll
        for (int ni=0;ni<4;++ni)
          acc[mi][ni] = MFMA_BF16(afr[mi], bfr[ni], acc[mi][ni]);
    }
    asm volatile("s_waitcnt vmcnt(0)" ::: "memory");
    __syncthreads();
  }

  const int crow0 = bm*128 + wm*64;
  const int ccol0 = bn*128 + wn*64;
#pragma unroll
  for (int ni=0;ni<4;++ni){
    const int col = ccol0 + ni*16 + c16;
    const float bsum = bih[col] + bhh[col];
#pragma unroll
    for (int mi=0;mi<4;++mi){
      const int row = crow0 + mi*16 + rq*4;
#pragma unroll
      for (int r=0;r<4;++r)
        C[(size_t)(row+r)*GDIM + col] = acc[mi][ni][r] + bsum;
    }
  }
}

// ---------------- persistent recurrence, 8x32 batch x hidden decomposition ------
// 256 blocks x 512 threads = 8 batch-groups (bq: 8 rows) x 32 hidden-groups
// (hg: 32 cols -> 128 gate rows). Block (bq,hg) reads h[8 rows][1024] = 16 KB
// -> total LLC h-traffic 4 MB/step (vs 8 MB at 64 hidden-groups).
// Sync: monotone per-producer flags at LLC; wave 0 lanes 0-31 poll (one flag
// per lane; R8-proven). Producer: 32 lanes store slice (16B), drain, flag.
// Waves: kq = wv>>1 (K quarter), rh = wv&1 (gate-row half, 64 rows).
// MFMA M=16 with 8 valid batch rows (rows 8-15 of hls are stale; their outputs
// are discarded) -- MFMA is far from the bottleneck.
__global__ __launch_bounds__(512,1) void lstm_rec(
    const unsigned short* __restrict__ whhb,   // bf16 [4096][1024]
    const float* __restrict__ xproj,           // fp32 [nsteps*64][4096]
    unsigned short* __restrict__ hring,        // bf16 [2][64*1024] (linear)
    float* __restrict__ cstate,                // fp32 [64*1024]
    float* __restrict__ outp,                  // fp32 d_out base
    unsigned int* __restrict__ bar,            // [8*32] flags, stride 32 uints
    int t0, int nsteps)
{
  const int tid = threadIdx.x;
  const int wv = tid >> 6, l = tid & 63;
  const int kq = wv >> 1, rh = wv & 1;
  const int c16 = l & 15, rq = l >> 4;
  const int bq = blockIdx.x >> 5;             // batch group 0..7 (8 rows)
  const int hg = blockIdx.x & 31;             // hidden group 0..31 (32 cols)
  const int hc0 = hg * 32;
  const int b0  = bq * 8;
  const int em = tid >> 5, ec = tid & 31;     // epilogue (batch,col), tid<256
  const int sb = tid >> 6, scl = tid & 63;    // staging (row, chunk base)

  __shared__ s16x8 hls[16*128];                         // 32 KB staged h (rows 0-7 live)
  __shared__ float part[4*8*4*33];                      // 16.9 KB [kq][m][g][c pad33]
  __shared__ __align__(16) unsigned short hsh[8*32];    // 512 B h bf16 staging

  // ---- W_hh slice -> registers: gate row n = rh*64 + nt*16 + c16 (0..127),
  //      col_loc = n>>2, g = n&3; whh row = g*HID + hc0 + col_loc;
  //      k = kq*256 + ks*32 + rq*8
  s16x8 breg[4][8];
#pragma unroll
  for (int nt = 0; nt < 4; ++nt){
    const int n = rh*64 + nt*16 + c16;
    const size_t grow = (size_t)(n & 3)*HID + hc0 + (n >> 2);
#pragma unroll
    for (int ks = 0; ks < 8; ++ks)
      breg[nt][ks] = *(const s16x8*)(whhb + grow*HID + kq*256 + ks*32 + rq*8);
  }

  // zero stale hls rows 8-15 once (avoid NaN garbage; outputs discarded anyway)
  hls[1024 + tid] = (s16x8){0,0,0,0,0,0,0,0};
  hls[1536 + tid] = (s16x8){0,0,0,0,0,0,0,0};

  float creg = 0.f, xp[4] = {0.f,0.f,0.f,0.f};
  if (tid < 256){
    creg = cstate[(size_t)(b0+em)*HID + hc0 + ec];
#pragma unroll
    for (int g = 0; g < 4; ++g)
      xp[g] = xproj[(size_t)(b0+em)*GDIM + g*HID + hc0 + ec];
  }

  const unsigned int* myflag = bar + ((bq*32 + (l & 31)) << 5);

  for (int t = t0; t < t0 + nsteps; ++t){
    // ---- wave 0 lanes 0-31: poll domain flags (1 per lane)
    if (wv == 0 && l < 32){
      unsigned fv; int spins = 0;
      const unsigned ut = (unsigned)t;
      do {
        asm volatile("global_load_dword %0, %1, off sc0 sc1\n\ts_waitcnt vmcnt(0)"
                     : "=v"(fv) : "v"(myflag) : "memory");
        if (fv >= ut) break;
        if (++spins > 4) __builtin_amdgcn_s_sleep(1);
      } while (spins < (1 << 17));
    }
    __syncthreads();                                   // B0: h^t ready

    // ---- stage 8 rows x 1024 cols: 2 x 16B per thread, swizzled LDS write
    {
      const unsigned short* gb = hring + (size_t)(t & 1)*65536
                               + (size_t)(b0 + sb)*HID;
      u32x4 t0v, t1v;
      asm volatile("global_load_dwordx4 %0, %1, off sc0 sc1"
                   : "=v"(t0v) : "v"(gb + scl*8));
      asm volatile("global_load_dwordx4 %0, %1, off sc0 sc1"
                   : "=v"(t1v) : "v"(gb + (scl + 64)*8));
      asm volatile("s_waitcnt vmcnt(0)" ::: "memory");
      __builtin_amdgcn_sched_barrier(0);
      const int c0 = scl, c1 = scl + 64;
      hls[sb*128 + ((c0 & ~7) | ((c0 & 7) ^ (sb & 7)))] = __builtin_bit_cast(s16x8, t0v);
      hls[sb*128 + ((c1 & ~7) | ((c1 & 7) ^ (sb & 7)))] = __builtin_bit_cast(s16x8, t1v);
    }
    __syncthreads();                                   // B1: hls ready

    // ---- MFMA: 4 n-tiles x 8 k-slices (4 independent chains)
    f32x4 acc[4];
#pragma unroll
    for (int nt = 0; nt < 4; ++nt) acc[nt] = (f32x4){0.f,0.f,0.f,0.f};
#pragma unroll
    for (int ks = 0; ks < 8; ++ks){
      const int c = kq*32 + ks*4 + rq;
      const s16x8 af = hls[c16*128 + ((c & ~7) | ((c & 7) ^ (c16 & 7)))];
#pragma unroll
      for (int nt = 0; nt < 4; ++nt)
        acc[nt] = MFMA_BF16(af, breg[nt][ks], acc[nt]);
    }

    // ---- partials -> LDS, g-major pad-33: valid batch rows m = rq*4+r < 8
    if (rq < 2){
#pragma unroll
      for (int nt = 0; nt < 4; ++nt){
        const int g = c16 & 3;
        const int cl = rh*16 + nt*4 + (c16 >> 2);
#pragma unroll
        for (int r = 0; r < 4; ++r){
          const int m = rq*4 + r;
          part[((kq*8 + m)*4 + g)*33 + cl] = acc[nt][r];
        }
      }
    }
    __syncthreads();                                   // B2: partials ready

    // ---- epilogue (256 threads): reduce 4 K-quarters, activations, state
    float hval = 0.f;
    if (tid < 256){
      float v[4];
#pragma unroll
      for (int g = 0; g < 4; ++g){
        v[g] = xp[g]
             + part[((0*8 + em)*4 + g)*33 + ec]
             + part[((1*8 + em)*4 + g)*33 + ec]
             + part[((2*8 + em)*4 + g)*33 + ec]
             + part[((3*8 + em)*4 + g)*33 + ec];
      }
      const float ig = 1.f/(1.f + __expf(-v[0]));
      const float fg = 1.f/(1.f + __expf(-v[1]));
      const float gg = tanhf(v[2]);
      const float og = 1.f/(1.f + __expf(-v[3]));
      creg = fg*creg + ig*gg;
      hval = og * tanhf(creg);
      hsh[em*32 + ec] = f2bf(hval);
    }
    __syncthreads();                                   // B3: hsh ready

    // ---- critical path: 32 lanes store slice (8 rows x 64B) -> drain -> flag
    if (tid < 32){
      const int row = tid >> 2, q = tid & 3;
      const unsigned short* hp = hring + (size_t)((t+1) & 1)*65536
                               + (size_t)(b0 + row)*HID + hc0 + q*8;
      u32x4 hv = *(const u32x4*)&hsh[row*32 + q*8];
      asm volatile("global_store_dwordx4 %0, %1, off sc0 sc1"
                   :: "v"(hp), "v"(hv) : "memory");
      asm volatile("s_waitcnt vmcnt(0)" ::: "memory");
      if (tid == 0){
        unsigned int* fp = bar + ((bq*32 + hg) << 5);
        unsigned int fv = (unsigned int)(t + 1);
        asm volatile("global_store_dword %0, %1, off sc0 sc1"
                     :: "v"(fp), "v"(fv) : "memory");
      }
    }

    // ---- off critical path: outputs, final state, xproj prefetch
    if (tid < 256){
      const size_t oidx = (size_t)(b0+em)*HID + hc0 + ec;
      outp[(size_t)t*65536 + oidx] = hval;
      if (t == SEQ-1){
        outp[(size_t)SEQ*65536 + oidx]         = hval;   // h_last
        outp[(size_t)SEQ*65536 + 65536 + oidx] = creg;   // c_last
      }
      if (t+1 < t0 + nsteps){
        const size_t xrow = (size_t)(t+1 - t0)*NBATCH + (b0+em);
#pragma unroll
        for (int g = 0; g < 4; ++g)
          xp[g] = xproj[xrow*GDIM + g*HID + hc0 + ec];
      }
    }
  }

  if (tid < 256)
    cstate[(size_t)(b0+em)*HID + hc0 + ec] = creg;
}

// ---------------------------------------------------------------------------
extern "C" void kernel_launch(void* const* d_in, const int* in_sizes, int n_in,
                              void* d_out, int out_size, void* d_ws, size_t ws_size,
                              hipStream_t stream)
{
  const float* inp = (const float*)d_in[0];
  const float* wih = (const float*)d_in[1];
  const float* whh = (const float*)d_in[2];
  const float* bih = (const float*)d_in[3];
  const float* bhh = (const float*)d_in[4];
  const float* h0  = (const float*)d_in[5];
  const float* c0  = (const float*)d_in[6];
  float* outp = (float*)d_out;

  auto alignup = [](size_t x){ return (x + 255) & ~(size_t)255; };
  auto need = [&](size_t ch)->size_t{
    size_t s = 0;
    s += alignup(ch*64*4096*4);          // xproj chunk
    s += alignup(ch*64*1024*2);          // in_bf16 chunk
    s += alignup((size_t)4096*1024*2);   // wih_bf16
    s += alignup((size_t)4096*1024*2);   // whh_bf16
    s += alignup((size_t)2*64*1024*2);   // h ring (2 slots)
    s += alignup((size_t)64*1024*4);     // cstate
    s += alignup((size_t)256*32*4);      // flags
    return s;
  };
  int CH = 512;
  while (CH > 2 && need(CH) > ws_size) CH >>= 1;

  char* w = (char*)d_ws;
  float*          xproj  = (float*)w;          w += alignup((size_t)CH*64*4096*4);
  unsigned short* in_bf  = (unsigned short*)w; w += alignup((size_t)CH*64*1024*2);
  unsigned short* wih_bf = (unsigned short*)w; w += alignup((size_t)4096*1024*2);
  unsigned short* whh_bf = (unsigned short*)w; w += alignup((size_t)4096*1024*2);
  unsigned short* hring  = (unsigned short*)w; w += alignup((size_t)2*64*1024*2);
  float*          cst    = (float*)w;          w += alignup((size_t)64*1024*4);
  unsigned int*   bar    = (unsigned int*)w;

  hipMemsetAsync(bar, 0, 256*32*4, stream);

  cvt_bf16<<<4096, 256, 0, stream>>>(wih, wih_bf, 4096*1024/4);
  cvt_bf16<<<4096, 256, 0, stream>>>(whh, whh_bf, 4096*1024/4);
  init_state<<<256, 256, 0, stream>>>(h0, c0, hring, cst);

  const int nch = SEQ / CH;
  for (int ci = 0; ci < nch; ++ci){
    const int t0 = ci * CH;
    const int n4 = CH*64*1024/4;
    cvt_bf16<<<(n4+255)/256, 256, 0, stream>>>(inp + (size_t)t0*65536, in_bf, n4);
    gemm_xproj<<<dim3((CH*64/128)*32), 256, 0, stream>>>(in_bf, wih_bf, bih, bhh,
                                                         xproj, CH*64);
    lstm_rec<<<dim3(256), dim3(512), 0, stream>>>(whh_bf, xproj, hring, cst, outp,
                                                  bar, t0, CH);
  }
}